// Round 6
// baseline (1095.308 us; speedup 1.0000x reference)
//
#include <hip/hip_runtime.h>

typedef int i32x4 __attribute__((ext_vector_type(4)));

static constexpr int M_TOK = 16384;       // B*S
static constexpr int D_IN  = 2048;
static constexpr int H_FF  = 5632;
static constexpr int NW    = H_FF * D_IN; // 11534336

__device__ __forceinline__ void async16(const void* g, void* l) {
    __builtin_amdgcn_global_load_lds((__attribute__((address_space(1))) void*)g,
                                     (__attribute__((address_space(3))) void*)l,
                                     16, 0, 0);
}

// raw workgroup barrier WITHOUT the vmcnt(0)/lgkmcnt(0) drain __syncthreads emits.
__device__ __forceinline__ void sbar() {
    asm volatile("" ::: "memory");
    __builtin_amdgcn_s_barrier();
    asm volatile("" ::: "memory");
}
// counted waits; sched_barrier(0) after lgkm keeps dependent MFMAs below the wait (rule 18)
#define WAIT_LGKM(n) { asm volatile("s_waitcnt lgkmcnt(" #n ")" ::: "memory"); \
                       __builtin_amdgcn_sched_barrier(0); }
#define WAIT_VM(n)   { asm volatile("s_waitcnt vmcnt(" #n ")" ::: "memory"); }

// ---------------- weight abs-mean reduction, FP64 accumulate ----------------
__global__ void absum_partial(const float4* __restrict__ w, int n4, double* __restrict__ part) {
    __shared__ double s[256];
    const int t = threadIdx.x;
    double acc = 0.0;
    for (int i = blockIdx.x * 256 + t; i < n4; i += gridDim.x * 256) {
        float4 v = w[i];
        acc += fabs((double)v.x) + fabs((double)v.y) + fabs((double)v.z) + fabs((double)v.w);
    }
    s[t] = acc;
    __syncthreads();
    for (int o = 128; o > 0; o >>= 1) {
        if (t < o) s[t] += s[t + o];
        __syncthreads();
    }
    if (t == 0) part[blockIdx.x] = s[0];
}

__global__ void finalize_scales(const double* __restrict__ parts, double* __restrict__ scales,
                                int nblocks, double inv_n) {
    const int t = threadIdx.x;
    if (t < 3) {
        const double* p = parts + t * nblocks;
        double s = 0.0;
        for (int i = 0; i < nblocks; ++i) s += p[i];
        double c = fmax(s * inv_n, 1e-5);   // clip(mean|w|, EPS)
        scales[t * 2]     = 1.0 / c;        // quantization scale (fp64)
        scales[t * 2 + 1] = c;              // dequant coeff (fp64)
    }
}

// ---------------- weight ternarization (FP64 rounding decision) -> int8 {-1,0,1} ----------
__global__ void quant_w_kernel(const float4* __restrict__ w, unsigned int* __restrict__ tw,
                               const double* __restrict__ scales, int idx, int n4) {
    const double s = scales[idx * 2];
    const int stride = gridDim.x * blockDim.x;
    for (int i = blockIdx.x * blockDim.x + threadIdx.x; i < n4; i += stride) {
        float4 v = w[i];
        int q0 = (int)fmin(fmax(rint((double)v.x * s), -1.0), 1.0);
        int q1 = (int)fmin(fmax(rint((double)v.y * s), -1.0), 1.0);
        int q2 = (int)fmin(fmax(rint((double)v.z * s), -1.0), 1.0);
        int q3 = (int)fmin(fmax(rint((double)v.w * s), -1.0), 1.0);
        tw[i] = (unsigned int)((q0 & 255) | ((q1 & 255) << 8) |
                               ((q2 & 255) << 16) | ((q3 & 255) << 24));
    }
}

// ---------------- x: rmsnorm + int8 absmax quant, FP64 stats & rounding ----------------
__global__ void quant_x_kernel(const float* __restrict__ x, signed char* __restrict__ qx,
                               double* __restrict__ cx) {
    __shared__ double ssum[256];
    __shared__ float  smax[256];
    const int token = blockIdx.x;
    const int t = threadIdx.x;
    const float4* xr = (const float4*)(x + (size_t)token * D_IN);
    float4 v0 = xr[t];
    float4 v1 = xr[t + 256];
    double ss = (double)v0.x*v0.x + (double)v0.y*v0.y + (double)v0.z*v0.z + (double)v0.w*v0.w
              + (double)v1.x*v1.x + (double)v1.y*v1.y + (double)v1.z*v1.z + (double)v1.w*v1.w;
    float mx = fmaxf(fmaxf(fmaxf(fabsf(v0.x), fabsf(v0.y)), fmaxf(fabsf(v0.z), fabsf(v0.w))),
                     fmaxf(fmaxf(fabsf(v1.x), fabsf(v1.y)), fmaxf(fabsf(v1.z), fabsf(v1.w))));
    ssum[t] = ss; smax[t] = mx;
    __syncthreads();
    for (int o = 128; o > 0; o >>= 1) {
        if (t < o) { ssum[t] += ssum[t + o]; smax[t] = fmaxf(smax[t], smax[t + o]); }
        __syncthreads();
    }
    const double ms    = ssum[0] * (1.0 / (double)D_IN);
    const double r     = 1.0 / sqrt(ms + 1e-6);
    const double den   = fmax((double)smax[0] * r, 1e-5);   // clip(max|xn|, EPS)
    const double scale = 127.0 / den;
    if (t == 0) cx[token] = den * (1.0 / 127.0);

    int q0 = (int)fmin(fmax(rint(((double)v0.x * r) * scale), -128.0), 127.0);
    int q1 = (int)fmin(fmax(rint(((double)v0.y * r) * scale), -128.0), 127.0);
    int q2 = (int)fmin(fmax(rint(((double)v0.z * r) * scale), -128.0), 127.0);
    int q3 = (int)fmin(fmax(rint(((double)v0.w * r) * scale), -128.0), 127.0);
    int q4 = (int)fmin(fmax(rint(((double)v1.x * r) * scale), -128.0), 127.0);
    int q5 = (int)fmin(fmax(rint(((double)v1.y * r) * scale), -128.0), 127.0);
    int q6 = (int)fmin(fmax(rint(((double)v1.z * r) * scale), -128.0), 127.0);
    int q7 = (int)fmin(fmax(rint(((double)v1.w * r) * scale), -128.0), 127.0);
    unsigned int* qr = (unsigned int*)(qx + (size_t)token * D_IN);
    qr[t]       = (unsigned int)((q0 & 255) | ((q1 & 255) << 8) | ((q2 & 255) << 16) | ((q3 & 255) << 24));
    qr[t + 256] = (unsigned int)((q4 & 255) | ((q5 & 255) << 8) | ((q6 & 255) << 16) | ((q7 & 255) << 24));
}

// ---------------- h: rmsnorm + quant IN-PLACE per token (int8 overlay), FP64 stats --------
__global__ void quant_h_kernel(float* __restrict__ h, double* __restrict__ ch) {
    __shared__ double ssum[256];
    __shared__ float  smax[256];
    const int token = blockIdx.x;
    const int t = threadIdx.x;
    float* hr = h + (size_t)token * H_FF;
    const float2* h2 = (const float2*)hr;
    float2 vals[11];                      // 5632 floats = 2816 float2 = 256*11
    double ss = 0.0;
    float mx = 0.f;
#pragma unroll
    for (int k = 0; k < 11; ++k) {
        float2 v = h2[t + 256 * k];
        vals[k] = v;
        ss += (double)v.x * (double)v.x + (double)v.y * (double)v.y;
        mx = fmaxf(mx, fmaxf(fabsf(v.x), fabsf(v.y)));
    }
    ssum[t] = ss; smax[t] = mx;
    __syncthreads();
    for (int o = 128; o > 0; o >>= 1) {
        if (t < o) { ssum[t] += ssum[t + o]; smax[t] = fmaxf(smax[t], smax[t + o]); }
        __syncthreads();
    }
    const double ms    = ssum[0] * (1.0 / (double)H_FF);
    const double r     = 1.0 / sqrt(ms + 1e-6);
    const double den   = fmax((double)smax[0] * r, 1e-5);
    const double scale = 127.0 / den;
    if (t == 0) ch[token] = den * (1.0 / 127.0);
    unsigned short* qr = (unsigned short*)hr;   // in-place overlay, same token row
#pragma unroll
    for (int k = 0; k < 11; ++k) {
        int a = (int)fmin(fmax(rint(((double)vals[k].x * r) * scale), -128.0), 127.0);
        int b = (int)fmin(fmax(rint(((double)vals[k].y * r) * scale), -128.0), 127.0);
        qr[t + 256 * k] = (unsigned short)((a & 255) | ((b & 255) << 8));
    }
}

// LDS geometry: 64B rows, 16B slots XOR-swizzled by (row>>1)&3 (SQ_LDS_BANK_CONFLICT=0
// verified). 2 buffers x 24KB = 48KB -> 2 blocks/CU. Registers <=128/wave (acc=64,
// frags=32) -> 16 waves/CU. Cross-block TLP hides the vmcnt(0)+barrier drain (m97
// mechanism); rounds 2-5 were register-bound at 8 waves/CU (252 regs) and lockstepped.

// ---------------- fused GEMM1+2, i8 MFMA, 2-block/CU m97-style schedule -------------------
// BM=256, BN=64, BK=64, 512 threads (8 waves: 4M x 2N, 64x32 per wave per gemm).
__global__ void __launch_bounds__(512, 4) gemm12_kernel(
    const signed char* __restrict__ qx,
    const signed char* __restrict__ tw1,   // tw2 = tw1 + NW (contiguous in workspace)
    const double* __restrict__ cx,
    const double* __restrict__ scales,
    float* __restrict__ h)
{
    // per buffer: A [0,16384)  B1 [16384,20480)  B2 [20480,24576)
    __shared__ __attribute__((aligned(16))) signed char lds[2][24576];

    const int t = threadIdx.x;
    // grid 5632 = 8 XCD x 704; bn-fastest within chunk -> each XCD owns 8 bm-slabs
    const int swz = (blockIdx.x & 7) * 704 + (blockIdx.x >> 3);
    const int bm  = swz / 88;    // 0..63
    const int bn  = swz % 88;    // 0..87

    const int srow = t >> 2;           // 0..127
    const int scol = (((t & 3) ^ ((t >> 3) & 3)) << 4);   // inverse-swizzled global slot
    const signed char* gA = qx + (size_t)(bm * 256 + srow) * D_IN + scol;
    const size_t arstep = (size_t)128 * D_IN;
    // combined B1|B2 staging: waves 0-3 (srow<64) load B1 rows, waves 4-7 load B2 rows
    const int brow = srow & 63;
    const signed char* gB = tw1 + (srow >= 64 ? (size_t)NW : (size_t)0)
                                + (size_t)(bn * 64 + brow) * D_IN + scol;
    const int l16 = t * 16;

    const int lane = t & 63;
    const int wv = t >> 6;        // 0..7
    const int wm = wv & 3;        // 4 M-waves (64 rows each)
    const int wn = wv >> 2;       // 2 N-waves (32 cols each per gemm)
    const int lm = lane & 15;
    const int kg = lane >> 4;
    const int koff  = ((kg ^ ((lm >> 1) & 3)) << 4);      // swizzled read slot
    const int abase = (wm * 64 + lm) * 64 + koff;         // + i*1024, i=0..3
    const int bbase = 16384 + (wn * 32 + lm) * 64 + koff; // + j*1024 (j=0..1); B2 at +4096

    const i32x4 izero = {0, 0, 0, 0};
    i32x4 acc1[4][2], acc2[4][2];
#pragma unroll
    for (int i = 0; i < 4; ++i)
#pragma unroll
        for (int j = 0; j < 2; ++j) { acc1[i][j] = izero; acc2[i][j] = izero; }

    constexpr int NT = D_IN / 64;   // 32 K-tiles

#define STAGE12(buf, kt) { const int go = (kt) * 64;                         \
        async16(gA + go,          &lds[buf][l16]);                           \
        async16(gA + arstep + go, &lds[buf][8192 + l16]);                    \
        async16(gB + go,          &lds[buf][16384 + l16]); }

    STAGE12(0, 0);
    WAIT_VM(0); sbar();

    for (int kt = 0; kt < NT; ++kt) {
        const int cur = kt & 1;
        if (kt + 1 < NT) STAGE12(cur ^ 1, kt + 1);

        i32x4 a[4], b1[2], b2[2];
#pragma unroll
        for (int i = 0; i < 4; ++i) a[i] = *(const i32x4*)&lds[cur][abase + i * 1024];
#pragma unroll
        for (int j = 0; j < 2; ++j) b1[j] = *(const i32x4*)&lds[cur][bbase + j * 1024];
        __builtin_amdgcn_sched_barrier(0);   // pin: (a,b1) issue before b2
#pragma unroll
        for (int j = 0; j < 2; ++j) b2[j] = *(const i32x4*)&lds[cur][bbase + 4096 + j * 1024];

        WAIT_LGKM(2);                        // a,b1 resident; b2's 2 reads in banks
        __builtin_amdgcn_s_setprio(1);
#pragma unroll
        for (int i = 0; i < 4; ++i)
#pragma unroll
            for (int j = 0; j < 2; ++j)
                acc1[i][j] = __builtin_amdgcn_mfma_i32_16x16x64_i8(a[i], b1[j], acc1[i][j], 0, 0, 0);
        __builtin_amdgcn_s_setprio(0);
        WAIT_LGKM(0);                        // b2 resident
        __builtin_amdgcn_s_setprio(1);
#pragma unroll
        for (int i = 0; i < 4; ++i)
#pragma unroll
            for (int j = 0; j < 2; ++j)
                acc2[i][j] = __builtin_amdgcn_mfma_i32_16x16x64_i8(a[i], b2[j], acc2[i][j], 0, 0, 0);
        __builtin_amdgcn_s_setprio(0);

        WAIT_VM(0);                          // next tile staged (other block hides drain)
        sbar();
    }
#undef STAGE12

    // epilogue: exact int accumulators, FP64 scale products, fp32 silu
    const double cw1 = scales[1];
    const double cw2 = scales[3];
#pragma unroll
    for (int i = 0; i < 4; ++i) {
#pragma unroll
        for (int v = 0; v < 4; ++v) {
            const int row = bm * 256 + wm * 64 + i * 16 + kg * 4 + v;
            const double c  = cx[row];
            const double s1 = c * cw1, s2 = c * cw2;
            float* hp = h + (size_t)row * H_FF + bn * 64 + wn * 32 + lm;
#pragma unroll
            for (int j = 0; j < 2; ++j) {
                float g  = (float)((double)acc1[i][j][v] * s1);
                float u  = (float)((double)acc2[i][j][v] * s2);
                float sg = g / (1.0f + expf(-g));   // silu
                hp[j * 16] = sg * u;
            }
        }
    }
}

// ---------------- GEMM3: i8 h-overlay x ternary w3, same 2-block/CU schedule --------------
// BM=256, BN=128, BK=64, 512 threads (8 waves: 4M x 2N, 64x64 per wave).
__global__ void __launch_bounds__(512, 4) gemm3_kernel(
    const signed char* __restrict__ qh,
    const signed char* __restrict__ tw3,
    const double* __restrict__ ch,
    const double* __restrict__ scales,
    float* __restrict__ out)
{
    // per buffer: A [0,16384)  B [16384,24576)
    __shared__ __attribute__((aligned(16))) signed char lds[2][24576];

    const int t = threadIdx.x;
    // grid 1024 = 8 XCD x 128; each XCD owns 8 bm-slabs x all 16 bn
    const int swz = (blockIdx.x & 7) * 128 + (blockIdx.x >> 3);
    const int bm  = swz >> 4;    // 0..63
    const int bn  = swz & 15;    // 0..15

    const int srow = t >> 2;     // 0..127
    const int scol = (((t & 3) ^ ((t >> 3) & 3)) << 4);
    const size_t qh_stride = (size_t)4 * H_FF;   // bytes per token row (fp32 overlay)
    const signed char* gA = qh  + (size_t)(bm * 256 + srow) * qh_stride + scol;
    const signed char* gB = tw3 + (size_t)(bn * 128 + srow) * H_FF + scol;
    const size_t arstep = (size_t)128 * qh_stride;
    const int l16 = t * 16;

    const int lane = t & 63;
    const int wv = t >> 6;
    const int wm = wv & 3;        // 4 M-waves (64 rows each)
    const int wn = wv >> 2;       // 2 N-waves (64 cols each)
    const int lm = lane & 15;
    const int kg = lane >> 4;
    const int koff  = ((kg ^ ((lm >> 1) & 3)) << 4);
    const int abase = (wm * 64 + lm) * 64 + koff;          // + i*1024, i=0..3
    const int bbase = 16384 + (wn * 64 + lm) * 64 + koff;  // + j*1024, j=0..3

    const i32x4 izero = {0, 0, 0, 0};
    i32x4 acc[4][4];
#pragma unroll
    for (int i = 0; i < 4; ++i)
#pragma unroll
        for (int j = 0; j < 4; ++j) acc[i][j] = izero;

    constexpr int NT = H_FF / 64;   // 88 K-tiles

#define STAGE3(buf, kt) { const int go = (kt) * 64;                          \
        async16(gA + go,          &lds[buf][l16]);                           \
        async16(gA + arstep + go, &lds[buf][8192 + l16]);                    \
        async16(gB + go,          &lds[buf][16384 + l16]); }

    STAGE3(0, 0);
    WAIT_VM(0); sbar();

    for (int kt = 0; kt < NT; ++kt) {
        const int cur = kt & 1;
        if (kt + 1 < NT) STAGE3(cur ^ 1, kt + 1);

        i32x4 a[4], b[4];
#pragma unroll
        for (int i = 0; i < 4; ++i) a[i] = *(const i32x4*)&lds[cur][abase + i * 1024];
#pragma unroll
        for (int j = 0; j < 2; ++j) b[j] = *(const i32x4*)&lds[cur][bbase + j * 1024];
        __builtin_amdgcn_sched_barrier(0);   // pin: (a,b01) before b23
#pragma unroll
        for (int j = 2; j < 4; ++j) b[j] = *(const i32x4*)&lds[cur][bbase + j * 1024];

        WAIT_LGKM(2);                        // a,b0,b1 resident
        __builtin_amdgcn_s_setprio(1);
#pragma unroll
        for (int i = 0; i < 4; ++i)
#pragma unroll
            for (int j = 0; j < 2; ++j)
                acc[i][j] = __builtin_amdgcn_mfma_i32_16x16x64_i8(a[i], b[j], acc[i][j], 0, 0, 0);
        __builtin_amdgcn_s_setprio(0);
        WAIT_LGKM(0);                        // b2,b3 resident
        __builtin_amdgcn_s_setprio(1);
#pragma unroll
        for (int i = 0; i < 4; ++i)
#pragma unroll
            for (int j = 2; j < 4; ++j)
                acc[i][j] = __builtin_amdgcn_mfma_i32_16x16x64_i8(a[i], b[j], acc[i][j], 0, 0, 0);
        __builtin_amdgcn_s_setprio(0);

        WAIT_VM(0);
        sbar();
    }
#undef STAGE3

    const double cw3 = scales[5];
#pragma unroll
    for (int i = 0; i < 4; ++i) {
#pragma unroll
        for (int v = 0; v < 4; ++v) {
            const int row = bm * 256 + wm * 64 + i * 16 + kg * 4 + v;
            const double sc = ch[row] * cw3;
            float* op = out + (size_t)row * D_IN + bn * 128 + wn * 64 + lm;
#pragma unroll
            for (int j = 0; j < 4; ++j) op[j * 16] = (float)((double)acc[i][j][v] * sc);
        }
    }
}

// ---------------- launch ----------------
extern "C" void kernel_launch(void* const* d_in, const int* in_sizes, int n_in,
                              void* d_out, int out_size, void* d_ws, size_t ws_size,
                              hipStream_t stream) {
    const float* x  = (const float*)d_in[0];
    const float* w1 = (const float*)d_in[1];
    const float* w2 = (const float*)d_in[2];
    const float* w3 = (const float*)d_in[3];

    char* ws = (char*)d_ws;
    // workspace layout (bytes, 256-aligned); total = 437,544,960
    double*      scales = (double*)(ws + 0);           // 6 d
    double*      parts  = (double*)(ws + 256);         // 3*1024 d = 24576 B
    double*      cx     = (double*)(ws + 25088);       // 16384 d = 131072 B
    double*      ch     = (double*)(ws + 156416);      // 16384 d = 131072 B
    signed char* tw1    = (signed char*)(ws + 287744);      // 11,534,336 B
    signed char* tw2    = (signed char*)(ws + 11822080);    // = tw1 + NW (contiguous!)
    signed char* tw3    = (signed char*)(ws + 23356416);    // 11,534,336 B
    float*       hb     = (float*)(ws + 34891520);          // 369,098,752 B (int8 qh overlays in-place)
    signed char* qx     = (signed char*)(ws + 403990528);   // 33,554,432 B

    absum_partial<<<1024, 256, 0, stream>>>((const float4*)w1, NW / 4, parts);
    absum_partial<<<1024, 256, 0, stream>>>((const float4*)w2, NW / 4, parts + 1024);
    absum_partial<<<1024, 256, 0, stream>>>((const float4*)w3, NW / 4, parts + 2048);
    finalize_scales<<<1, 64, 0, stream>>>(parts, scales, 1024, 1.0 / (double)NW);
    quant_w_kernel<<<2048, 256, 0, stream>>>((const float4*)w1, (unsigned int*)tw1, scales, 0, NW / 4);
    quant_w_kernel<<<2048, 256, 0, stream>>>((const float4*)w2, (unsigned int*)tw2, scales, 1, NW / 4);
    quant_w_kernel<<<2048, 256, 0, stream>>>((const float4*)w3, (unsigned int*)tw3, scales, 2, NW / 4);
    quant_x_kernel<<<M_TOK, 256, 0, stream>>>(x, qx, cx);
    gemm12_kernel<<<5632, 512, 0, stream>>>(qx, tw1, cx, scales, hb);
    quant_h_kernel<<<M_TOK, 256, 0, stream>>>(hb, ch);
    gemm3_kernel<<<1024, 512, 0, stream>>>((const signed char*)hb, tw3, ch, scales, (float*)d_out);
}